// Round 6
// baseline (176.498 us; speedup 1.0000x reference)
//
#include <hip/hip_runtime.h>

// ResidualNetwork forward, MI355X (gfx950).
// Round 26: ILP4 WITH ASM-PINNED STAGE BATCHING. Unified model from r20-r25:
// per-SIMD MFMA busy always == demand (98-105k cyc); wall is set by per-wave
// pace ~230 cyc/MFMA-stage (invariant across weights-in-regs r20, LDS r21,
// 8-wave r23, rotation r25) -> dependency-starved waves: ILP2 gives nothing
// to issue during ~100cyc MFMA-result latency + repack. Source ILP4 (r22) was
// FISSIONED by the register allocator (c=0,1 then c=2,3, VGPR 56). Fix: pin
// all 4 accumulators live at every stage boundary via zero-cost
// asm("" : "+v"(..)x4) ties -> fission illegal, 4 independent MFMAs batched
// per stage, wave always has a ready MFMA during repack. Est VGPR ~115 < 128
// cap at (256,4). No x dbuf (one exposed x-wait per quad, ~10% amortized).
// Gates: FETCH ~24.7MB WRITE 16384KB (no spill); VGPR 100-128 (if ~40: pins
// failed, void); success MfmaUtil 75-90 / main 47-58us; if VGPR high + wall
// ~80us anyway -> structural roofline 3072x64cyc=82us, declare next round.

#define NPTS 4194304
#define NBLK 2048
#define WPB 4                       // waves per block (256 threads)
#define NWAVES (NBLK * WPB)         // 8192
#define NTILES (NPTS / 32)          // 131072
#define TPW (NTILES / NWAVES)       // 16 tiles per wave
#define NMM 24
#define ILP 4

typedef _Float16 h8 __attribute__((ext_vector_type(8)));
typedef float v16f __attribute__((ext_vector_type(16)));
typedef unsigned u4v __attribute__((ext_vector_type(4)));

// zero-cost register ties: forces all 4 values simultaneously live ->
// the register allocator cannot fission the ILP loops.
#define PIN4(a) asm volatile("" : "+v"(a[0]), "+v"(a[1]), "+v"(a[2]), "+v"(a[3]))

__device__ __forceinline__ v16f mm(h8 a, h8 b, v16f c) {
    return __builtin_amdgcn_mfma_f32_32x32x16_f16(a, b, c, 0, 0, 0);
}
__device__ __forceinline__ unsigned pkrtz(float a, float b) {
    return __builtin_bit_cast(unsigned, __builtin_amdgcn_cvt_pkrtz(a, b));
}
// relu on packed f16: 4x v_pk_max_f16
__device__ __forceinline__ h8 relu8(h8 h) {
    h8 z = {0, 0, 0, 0, 0, 0, 0, 0};
    return __builtin_elementwise_max(h, z);
}
// pack+relu of D regs 0-7 (rows sigma(k)): B fragment, sigma order
__device__ __forceinline__ h8 rc_lo(v16f d) {
    u4v u;
    u.x = pkrtz(d[0], d[1]); u.y = pkrtz(d[2], d[3]);
    u.z = pkrtz(d[4], d[5]); u.w = pkrtz(d[6], d[7]);
    return relu8(__builtin_bit_cast(h8, u));
}
// pack+relu of D regs 8-15 (rows 16+sigma(k)): same sigma order
__device__ __forceinline__ h8 rc_hi(v16f d) {
    u4v u;
    u.x = pkrtz(d[8], d[9]);   u.y = pkrtz(d[10], d[11]);
    u.z = pkrtz(d[12], d[13]); u.w = pkrtz(d[14], d[15]);
    return relu8(__builtin_bit_cast(h8, u));
}

// ---------------- prepack: fused A fragments, sigma-permuted K ---------------
// q=0: layer0 (k rows: x0,x1,x2 @ rr<3, bias col rr==3, pass A[10][rr==3]=1)
// q=1: layer1 dense (w1,b1, pass row 10)
// q=2+2l: fused block A: m0-9=Wr1^T|rr==10:Br1 ; m16-25=Wr2^T|rr==10:Br2+Br3;
//         m26,rr==10: 1 (ones pass)
// q=3+2l: W3 shifted: m16-25 = Wr3^T (rows 0-15 and 26 zero -> srcC passthru)
// q=22: layer8 dense (w8,b8, pass row 10)   q=23: out row m=0 (w9,b9)
__global__ __launch_bounds__(64) void prepack(
    const float* __restrict__ w0, const float* __restrict__ b0,
    const float* __restrict__ w1, const float* __restrict__ b1,
    const float* __restrict__ Wr1, const float* __restrict__ Br1,
    const float* __restrict__ Wr2, const float* __restrict__ Br2,
    const float* __restrict__ Wr3, const float* __restrict__ Br3,
    const float* __restrict__ w8, const float* __restrict__ b8,
    const float* __restrict__ w9, const float* __restrict__ b9,
    h8* __restrict__ tab)
{
    const int q = blockIdx.x, l = threadIdx.x;
    const int m = l & 31, g = l >> 5;
    h8 v;
#pragma unroll
    for (int j = 0; j < 8; ++j) {
        const int rr = (j & 3) + 8 * (j >> 2) + 4 * g;  // sigma(k)
        float a = 0.0f;
        if (q == 0) {
            if (m < 10 && rr < 3)        a = w0[rr * 10 + m];
            else if (m < 10 && rr == 3)  a = b0[m];
            else if (m == 10 && rr == 3) a = 1.0f;
        } else if (q == 1 || q == 22) {
            const float* W = (q == 1) ? w1 : w8;
            const float* B = (q == 1) ? b1 : b8;
            if (m < 10 && rr < 10)        a = W[rr * 10 + m];
            else if (m < 10 && rr == 10)  a = B[m];
            else if (m == 10 && rr == 10) a = 1.0f;
        } else if (q == 23) {
            if (m == 0 && rr < 10)       a = w9[rr];
            else if (m == 0 && rr == 10) a = b9[0];
        } else if (((q - 2) & 1) == 0) {           // fused W1|W2 block
            const int bl = (q - 2) >> 1;
            if (m < 10) {
                if (rr < 10)       a = Wr1[bl * 100 + rr * 10 + m];
                else if (rr == 10) a = Br1[bl * 10 + m];
            } else if (m >= 16 && m < 26) {
                if (rr < 10)       a = Wr2[bl * 100 + rr * 10 + (m - 16)];
                else if (rr == 10) a = Br2[bl * 10 + (m - 16)] + Br3[bl * 10 + (m - 16)];
            } else if (m == 26 && rr == 10) {
                a = 1.0f;                          // ones pass for next layer
            }
        } else {                                   // W3, output rows 16-25
            const int bl = (q - 3) >> 1;
            if (m >= 16 && m < 26 && rr < 10)
                a = Wr3[bl * 100 + rr * 10 + (m - 16)];
        }
        v[j] = (_Float16)a;
    }
    tab[q * 64 + l] = v;
}

// ---- main kernel: fused 24-MFMA chain, pinned 4-chain batches, LDS wts -----
__global__ __launch_bounds__(256, 4) void resnet_fwd(
    const float* __restrict__ x,
    const h8* __restrict__ tab,
    float* __restrict__ out)
{
    // stage the 24 A-fragment planes (24*64*16B = 24.6 KB) once per block
    __shared__ h8 sA[NMM * 64];
    for (int i = threadIdx.x; i < NMM * 64; i += 256) sA[i] = tab[i];
    __syncthreads();

    const int lane = threadIdx.x & 63;
    const int wv = blockIdx.x * WPB + (threadIdx.x >> 6);
    const int col = lane & 31;
    const bool lo = lane < 32;

    // resident zero srcC
    v16f zero;
#pragma unroll
    for (int j = 0; j < 16; ++j) zero[j] = 0.0f;
    asm volatile("" : "+v"(zero));

    const long p0 = (long)wv * TPW * 32;          // first point index of wave
    const float* px = x + (p0 + col) * 3;         // per-lane x pointer
    float* po = out + p0 + col;                   // per-lane out pointer

    for (int t = 0; t < TPW; t += ILP) {
        // opaque lane index: stops LICM hoisting all 24 planes into regs
        int ln = lane;
        asm volatile("" : "+v"(ln));
        const h8* wp = &sA[ln];

        // layer-0 B for 4 tiles: lanes 0-31 carry (x0,x1,x2,1) in k-rows 0-3
        h8 hh[ILP];
#pragma unroll
        for (int c = 0; c < ILP; ++c) {
            float a0 = 0.f, a1 = 0.f, a2 = 0.f;
            if (lo) { a0 = px[c * 96 + 0]; a1 = px[c * 96 + 1];
                      a2 = px[c * 96 + 2]; }
            u4v u;
            u.x = pkrtz(a0, a1); u.y = pkrtz(a2, lo ? 1.0f : 0.0f);
            u.z = 0u; u.w = 0u;
            hh[c] = __builtin_bit_cast(h8, u);
        }
        PIN4(hh);

        // layer 0, layer 1 (one ds_read feeds all 4 chains)
        {
            h8 a0 = wp[0 * 64];
#pragma unroll
            for (int c = 0; c < ILP; ++c) hh[c] = rc_lo(mm(a0, hh[c], zero));
            PIN4(hh);
            h8 a1 = wp[1 * 64];
#pragma unroll
            for (int c = 0; c < ILP; ++c) hh[c] = rc_lo(mm(a1, hh[c], zero));
            PIN4(hh);
        }

        // residual blocks: 2 MFMA each (fused W1|W2, then W3 onto rows 16-26)
#pragma unroll
        for (int bl = 0; bl < 10; ++bl) {
            h8 a12 = wp[(2 + 2 * bl) * 64];
            h8 a3  = wp[(3 + 2 * bl) * 64];
            v16f d12[ILP];
#pragma unroll
            for (int c = 0; c < ILP; ++c) d12[c] = mm(a12, hh[c], zero);
            PIN4(d12);
#pragma unroll
            for (int c = 0; c < ILP; ++c) {
                h8 t1 = rc_lo(d12[c]);
                d12[c] = mm(a3, t1, d12[c]);
            }
            PIN4(d12);
#pragma unroll
            for (int c = 0; c < ILP; ++c) hh[c] = rc_hi(d12[c]);
            PIN4(hh);
        }

        // layer 8
        {
            h8 a8 = wp[22 * 64];
#pragma unroll
            for (int c = 0; c < ILP; ++c) hh[c] = rc_lo(mm(a8, hh[c], zero));
            PIN4(hh);
        }

        // output layer: D row 0 (lanes 0-31, reg 0) = result for 32 points
        {
            h8 a9 = wp[23 * 64];
#pragma unroll
            for (int c = 0; c < ILP; ++c) {
                v16f d = mm(a9, hh[c], zero);
                if (lo) po[c * 32] = d[0];
            }
        }

        px += ILP * 96;
        po += ILP * 32;
    }
}

extern "C" void kernel_launch(void* const* d_in, const int* in_sizes, int n_in,
                              void* d_out, int out_size, void* d_ws, size_t ws_size,
                              hipStream_t stream)
{
    const float* x   = (const float*)d_in[0];
    const float* w0  = (const float*)d_in[1];
    const float* b0  = (const float*)d_in[2];
    const float* w1  = (const float*)d_in[3];
    const float* b1  = (const float*)d_in[4];
    const float* Wr1 = (const float*)d_in[5];
    const float* Br1 = (const float*)d_in[6];
    const float* Wr2 = (const float*)d_in[7];
    const float* Br2 = (const float*)d_in[8];
    const float* Wr3 = (const float*)d_in[9];
    const float* Br3 = (const float*)d_in[10];
    const float* w8  = (const float*)d_in[11];
    const float* b8  = (const float*)d_in[12];
    const float* w9  = (const float*)d_in[13];
    const float* b9  = (const float*)d_in[14];
    float* out = (float*)d_out;
    h8* tab = (h8*)d_ws;   // 24 * 64 * 16B = 24.6 KB scratch

    hipLaunchKernelGGL(prepack, dim3(NMM), dim3(64), 0, stream,
                       w0, b0, w1, b1, Wr1, Br1, Wr2, Br2, Wr3, Br3,
                       w8, b8, w9, b9, tab);

    hipLaunchKernelGGL(resnet_fwd, dim3(NBLK), dim3(256), 0, stream,
                       x, (const h8*)tab, out);
}

// Round 7
// 172.979 us; speedup vs baseline: 1.0203x; 1.0203x over previous
//
#include <hip/hip_runtime.h>

// ResidualNetwork forward, MI355X (gfx950).
// Round 27: SCHED_GROUP_BARRIER STAGE CLUSTERING. Mechanism finally isolated:
// r25 pace = 12.4k cyc/pair = 2.25x the 24-stage critical path, and VGPR=40
// => compiler allocates ONE shared D buffer for both ILP chains -> emitted
// order mm0;wait;rc0;mm1;wait;rc1 -- every MFMA's ~130cyc latency exposed
// twice per stage (~460 cyc). Per-wave MFMA feed 64/460=14% x 3.6 waves = 50%
// = the MfmaUtil wall seen in ALL of r21-r26 (ILP/occupancy/prefetch never
// changed the within-wave schedule; PIN4 was satisfied via AGPRs). Fix: T19
// sched_group_barrier per stage: [MFMA x2] then [VALU x16] -- forces both
// chains' MFMAs back-to-back (distinct D bufs implied: mm1 precedes rc0 which
// reads mm0's dst), stage -> ~230 cyc, per-wave feed ~28% x 3.6 waves ~ 100%.
// x-loads made branchless (col=lane&31 valid for all lanes; hi lanes zeroed
// by selects) so the whole t-body stays ONE scheduling region for the SGBs.
// Geometry unchanged: 256thr, (256,4), grid 2048, LDS table, ILP2.
// Gates: VGPR 72-96 (if ~40 SGB ignored -> void, go inline-asm); MfmaUtil
// 75-95; main 45-55us; FETCH ~24.7MB WRITE 16384KB; absmax 0.

#define NPTS 4194304
#define NBLK 2048
#define WPB 4                       // waves per block (256 threads)
#define NWAVES (NBLK * WPB)         // 8192
#define NTILES (NPTS / 32)          // 131072
#define TPW (NTILES / NWAVES)       // 16 tiles per wave
#define NMM 24
#define ILP 2

typedef _Float16 h8 __attribute__((ext_vector_type(8)));
typedef float v16f __attribute__((ext_vector_type(16)));
typedef unsigned u4v __attribute__((ext_vector_type(4)));

// T19 masks: MFMA=0x8, VALU=0x2, DS_READ=0x100
#define SGB_MFMA(n) __builtin_amdgcn_sched_group_barrier(0x8, n, 0)
#define SGB_VALU(n) __builtin_amdgcn_sched_group_barrier(0x2, n, 0)

__device__ __forceinline__ v16f mm(h8 a, h8 b, v16f c) {
    return __builtin_amdgcn_mfma_f32_32x32x16_f16(a, b, c, 0, 0, 0);
}
__device__ __forceinline__ unsigned pkrtz(float a, float b) {
    return __builtin_bit_cast(unsigned, __builtin_amdgcn_cvt_pkrtz(a, b));
}
// relu on packed f16: 4x v_pk_max_f16
__device__ __forceinline__ h8 relu8(h8 h) {
    h8 z = {0, 0, 0, 0, 0, 0, 0, 0};
    return __builtin_elementwise_max(h, z);
}
// pack+relu of D regs 0-7 (rows sigma(k)): B fragment, sigma order
__device__ __forceinline__ h8 rc_lo(v16f d) {
    u4v u;
    u.x = pkrtz(d[0], d[1]); u.y = pkrtz(d[2], d[3]);
    u.z = pkrtz(d[4], d[5]); u.w = pkrtz(d[6], d[7]);
    return relu8(__builtin_bit_cast(h8, u));
}
// pack+relu of D regs 8-15 (rows 16+sigma(k)): same sigma order
__device__ __forceinline__ h8 rc_hi(v16f d) {
    u4v u;
    u.x = pkrtz(d[8], d[9]);   u.y = pkrtz(d[10], d[11]);
    u.z = pkrtz(d[12], d[13]); u.w = pkrtz(d[14], d[15]);
    return relu8(__builtin_bit_cast(h8, u));
}

// ---------------- prepack: fused A fragments, sigma-permuted K ---------------
// q=0: layer0 (k rows: x0,x1,x2 @ rr<3, bias col rr==3, pass A[10][rr==3]=1)
// q=1: layer1 dense (w1,b1, pass row 10)
// q=2+2l: fused block A: m0-9=Wr1^T|rr==10:Br1 ; m16-25=Wr2^T|rr==10:Br2+Br3;
//         m26,rr==10: 1 (ones pass)
// q=3+2l: W3 shifted: m16-25 = Wr3^T (rows 0-15 and 26 zero -> srcC passthru)
// q=22: layer8 dense (w8,b8, pass row 10)   q=23: out row m=0 (w9,b9)
__global__ __launch_bounds__(64) void prepack(
    const float* __restrict__ w0, const float* __restrict__ b0,
    const float* __restrict__ w1, const float* __restrict__ b1,
    const float* __restrict__ Wr1, const float* __restrict__ Br1,
    const float* __restrict__ Wr2, const float* __restrict__ Br2,
    const float* __restrict__ Wr3, const float* __restrict__ Br3,
    const float* __restrict__ w8, const float* __restrict__ b8,
    const float* __restrict__ w9, const float* __restrict__ b9,
    h8* __restrict__ tab)
{
    const int q = blockIdx.x, l = threadIdx.x;
    const int m = l & 31, g = l >> 5;
    h8 v;
#pragma unroll
    for (int j = 0; j < 8; ++j) {
        const int rr = (j & 3) + 8 * (j >> 2) + 4 * g;  // sigma(k)
        float a = 0.0f;
        if (q == 0) {
            if (m < 10 && rr < 3)        a = w0[rr * 10 + m];
            else if (m < 10 && rr == 3)  a = b0[m];
            else if (m == 10 && rr == 3) a = 1.0f;
        } else if (q == 1 || q == 22) {
            const float* W = (q == 1) ? w1 : w8;
            const float* B = (q == 1) ? b1 : b8;
            if (m < 10 && rr < 10)        a = W[rr * 10 + m];
            else if (m < 10 && rr == 10)  a = B[m];
            else if (m == 10 && rr == 10) a = 1.0f;
        } else if (q == 23) {
            if (m == 0 && rr < 10)       a = w9[rr];
            else if (m == 0 && rr == 10) a = b9[0];
        } else if (((q - 2) & 1) == 0) {           // fused W1|W2 block
            const int bl = (q - 2) >> 1;
            if (m < 10) {
                if (rr < 10)       a = Wr1[bl * 100 + rr * 10 + m];
                else if (rr == 10) a = Br1[bl * 10 + m];
            } else if (m >= 16 && m < 26) {
                if (rr < 10)       a = Wr2[bl * 100 + rr * 10 + (m - 16)];
                else if (rr == 10) a = Br2[bl * 10 + (m - 16)] + Br3[bl * 10 + (m - 16)];
            } else if (m == 26 && rr == 10) {
                a = 1.0f;                          // ones pass for next layer
            }
        } else {                                   // W3, output rows 16-25
            const int bl = (q - 3) >> 1;
            if (m >= 16 && m < 26 && rr < 10)
                a = Wr3[bl * 100 + rr * 10 + (m - 16)];
        }
        v[j] = (_Float16)a;
    }
    tab[q * 64 + l] = v;
}

// ---- main kernel: fused 24-MFMA chain, SGB stage clustering, LDS wts -------
__global__ __launch_bounds__(256, 4) void resnet_fwd(
    const float* __restrict__ x,
    const h8* __restrict__ tab,
    float* __restrict__ out)
{
    // stage the 24 A-fragment planes (24*64*16B = 24.6 KB) once per block
    __shared__ h8 sA[NMM * 64];
    for (int i = threadIdx.x; i < NMM * 64; i += 256) sA[i] = tab[i];
    __syncthreads();

    const int lane = threadIdx.x & 63;
    const int wv = blockIdx.x * WPB + (threadIdx.x >> 6);
    const int col = lane & 31;
    const bool lo = lane < 32;

    // resident zero srcC
    v16f zero;
#pragma unroll
    for (int j = 0; j < 16; ++j) zero[j] = 0.0f;
    asm volatile("" : "+v"(zero));

    const long p0 = (long)wv * TPW * 32;          // first point index of wave
    const float* px = x + (p0 + col) * 3;         // per-lane x pointer
    float* po = out + p0 + col;                   // per-lane out pointer

    for (int t = 0; t < TPW; t += ILP) {
        // opaque lane index: stops LICM hoisting all 24 planes into regs
        int ln = lane;
        asm volatile("" : "+v"(ln));
        const h8* wp = &sA[ln];

        // layer-0 B: branchless loads (col = lane&31 is valid for ALL lanes;
        // hi lanes zeroed by selects) -> no branch, one scheduling region.
        h8 hh[ILP];
#pragma unroll
        for (int c = 0; c < ILP; ++c) {
            float a0 = px[c * 96 + 0];
            float a1 = px[c * 96 + 1];
            float a2 = px[c * 96 + 2];
            a0 = lo ? a0 : 0.0f;
            a1 = lo ? a1 : 0.0f;
            a2 = lo ? a2 : 0.0f;
            u4v u;
            u.x = pkrtz(a0, a1); u.y = pkrtz(a2, lo ? 1.0f : 0.0f);
            u.z = 0u; u.w = 0u;
            hh[c] = __builtin_bit_cast(h8, u);
        }

        // layer 0
        {
            h8 a0 = wp[0 * 64];
            v16f d[ILP];
#pragma unroll
            for (int c = 0; c < ILP; ++c) d[c] = mm(a0, hh[c], zero);
            SGB_MFMA(2);
#pragma unroll
            for (int c = 0; c < ILP; ++c) hh[c] = rc_lo(d[c]);
            SGB_VALU(16);
        }
        // layer 1
        {
            h8 a1 = wp[1 * 64];
            v16f d[ILP];
#pragma unroll
            for (int c = 0; c < ILP; ++c) d[c] = mm(a1, hh[c], zero);
            SGB_MFMA(2);
#pragma unroll
            for (int c = 0; c < ILP; ++c) hh[c] = rc_lo(d[c]);
            SGB_VALU(16);
        }

        // residual blocks: [mm12 x2][rc_lo x2][mm3 x2][rc_hi x2] per block
#pragma unroll
        for (int bl = 0; bl < 10; ++bl) {
            h8 a12 = wp[(2 + 2 * bl) * 64];
            h8 a3  = wp[(3 + 2 * bl) * 64];
            v16f d12[ILP];
#pragma unroll
            for (int c = 0; c < ILP; ++c) d12[c] = mm(a12, hh[c], zero);
            SGB_MFMA(2);
            h8 t1[ILP];
#pragma unroll
            for (int c = 0; c < ILP; ++c) t1[c] = rc_lo(d12[c]);
            SGB_VALU(16);
#pragma unroll
            for (int c = 0; c < ILP; ++c) d12[c] = mm(a3, t1[c], d12[c]);
            SGB_MFMA(2);
#pragma unroll
            for (int c = 0; c < ILP; ++c) hh[c] = rc_hi(d12[c]);
            SGB_VALU(16);
        }

        // layer 8
        {
            h8 a8 = wp[22 * 64];
            v16f d[ILP];
#pragma unroll
            for (int c = 0; c < ILP; ++c) d[c] = mm(a8, hh[c], zero);
            SGB_MFMA(2);
#pragma unroll
            for (int c = 0; c < ILP; ++c) hh[c] = rc_lo(d[c]);
            SGB_VALU(16);
        }

        // output layer: D row 0 (lanes 0-31, reg 0) = result for 32 points
        {
            h8 a9 = wp[23 * 64];
            v16f d[ILP];
#pragma unroll
            for (int c = 0; c < ILP; ++c) d[c] = mm(a9, hh[c], zero);
            SGB_MFMA(2);
#pragma unroll
            for (int c = 0; c < ILP; ++c)
                if (lo) po[c * 32] = d[c][0];
        }

        px += ILP * 96;
        po += ILP * 32;
    }
}

extern "C" void kernel_launch(void* const* d_in, const int* in_sizes, int n_in,
                              void* d_out, int out_size, void* d_ws, size_t ws_size,
                              hipStream_t stream)
{
    const float* x   = (const float*)d_in[0];
    const float* w0  = (const float*)d_in[1];
    const float* b0  = (const float*)d_in[2];
    const float* w1  = (const float*)d_in[3];
    const float* b1  = (const float*)d_in[4];
    const float* Wr1 = (const float*)d_in[5];
    const float* Br1 = (const float*)d_in[6];
    const float* Wr2 = (const float*)d_in[7];
    const float* Br2 = (const float*)d_in[8];
    const float* Wr3 = (const float*)d_in[9];
    const float* Br3 = (const float*)d_in[10];
    const float* w8  = (const float*)d_in[11];
    const float* b8  = (const float*)d_in[12];
    const float* w9  = (const float*)d_in[13];
    const float* b9  = (const float*)d_in[14];
    float* out = (float*)d_out;
    h8* tab = (h8*)d_ws;   // 24 * 64 * 16B = 24.6 KB scratch

    hipLaunchKernelGGL(prepack, dim3(NMM), dim3(64), 0, stream,
                       w0, b0, w1, b1, Wr1, Br1, Wr2, Br2, Wr3, Br3,
                       w8, b8, w9, b9, tab);

    hipLaunchKernelGGL(resnet_fwd, dim3(NBLK), dim3(256), 0, stream,
                       x, (const h8*)tab, out);
}